// Round 8
// baseline (117.286 us; speedup 1.0000x reference)
//
#include <hip/hip_runtime.h>

// Depthwise 3x3 conv, NHWC, stride 1, SAME, fp32.
// x: (32,112,112,192), w: (3,3,1,192), b: (192), out: (32,112,112,192)
//
// R8: deep-pipelined streaming. Block = 128 threads (2 waves) = 16w x 8c4,
//     56 output rows (14 tiles x 4). LDS ring = 4 regions of 4 rows x 18
//     cols x 8 f4 (9216 B each, 36,864 B total -> 4 blocks/CU). Prefetch
//     DEPTH 2: tile t issues region t+3; steady-state waits vmcnt(18)/(16)
//     keep 2 regions + 2 tiles of stores in flight. Outstanding regions/CU
//     = 4 blocks x 2 = 8 (R6 had 3 -> 107 us; R7 had 2 -> 115 us).

constexpr int Bn = 32, Hn = 112, Wn = 112, Cn = 192, C4 = 48;
constexpr int WT = 16, CT = 8;        // 16 w-cols x 8 f4 = 32 channels
constexpr int WTiles = 7, CTiles = 6;
constexpr int NSTEP = 14, HG = 2;     // 56 output rows per block
constexpr int LWC = 18;               // staged halo cols
constexpr int ROWF4 = LWC * CT;       // 144 f4 per staged row
constexpr int REGF4 = 4 * ROWF4;      // 576 f4 per 4-row region = 9 chunks
constexpr int REGB = REGF4 * 16;      // 9216 B
constexpr int NSLOT = 4;              // ring regions; 36,864 B LDS

typedef float floatx4 __attribute__((ext_vector_type(4)));

#define VMWAIT(n) asm volatile("s_waitcnt vmcnt(" #n ")" ::: "memory")

__device__ __forceinline__ floatx4 fma4(floatx4 a, floatx4 b, floatx4 c) {
  c.x = fmaf(a.x, b.x, c.x);
  c.y = fmaf(a.y, b.y, c.y);
  c.z = fmaf(a.z, b.z, c.z);
  c.w = fmaf(a.w, b.w, c.w);
  return c;
}

__global__ __launch_bounds__(128, 2) void dwconv3x3_deep(
    const float* __restrict__ x,
    const float* __restrict__ wgt,   // (3,3,1,192)
    const float* __restrict__ bias,  // (192)
    float* __restrict__ out) {
  __shared__ floatx4 lds[NSLOT * REGF4];  // 36,864 B
  const int tid = (int)threadIdx.x;
  const int lane = tid & 63;
  const int wave = tid >> 6;  // 0 or 1

  // Chunked XCD swizzle (2688 % 8 == 0).
  int bid = blockIdx.x;
  int chk = gridDim.x >> 3;  // 336
  int sbid = (bid & 7) * chk + (bid >> 3);
  int c4t = sbid % CTiles; int tt = sbid / CTiles;
  int wt = tt % WTiles;    tt /= WTiles;
  int hg = tt % HG;        int b = tt / HG;

  const int hbase = hg * (4 * NSTEP);
  const int w0 = wt * WT;
  const int cbase = c4t * (CT * 4);   // float offset of channel tile
  const float* xb = x + (long)b * Hn * Wn * Cn;
  const int rstr = Wn * Cn;

  // Region = 9 chunks of 1 KB; wave0 owns chunks 0..4, wave1 owns 5..8.
  const int cstart = wave * 5;
  const int ccount = 5 - wave;        // 5 or 4
  // Per-chunk row-in-region + source column offset (region-invariant).
  int rr[5], colOff[5];
#pragma unroll
  for (int j = 0; j < 5; ++j) {
    int l = (cstart + j) * 64 + lane;       // f4 linear in region (0..575)
    int r = l / ROWF4;                      // 0..3
    int rem = l - r * ROWF4;
    int wi = rem >> 3, c4l = rem & 7;
    int wg = w0 + wi - 1;
    int wc = min(max(wg, 0), Wn - 1);       // clamp; w-validity in weights
    rr[j] = r;
    colOff[j] = wc * Cn + cbase + c4l * 4;
  }

  // Staged row s (s=0..57) = input h = hbase + s - 1. Region k = rows
  // 4k..4k+3 (k=0..14; region 14 rows 2,3 staged-but-unread). Tile t
  // consumes regions t, t+1. Prologue: regions 0..2.
#pragma unroll
  for (int k = 0; k < 3; ++k) {
#pragma unroll
    for (int j = 0; j < 5; ++j) {
      if (j < ccount) {
        int h = hbase + 4 * k + rr[j] - 1;
        int hc = min(max(h, 0), Hn - 1);
        const float* src = xb + (long)hc * rstr + colOff[j];
        char* dst = (char*)lds + k * REGB + (cstart + j) * 1024;
        __builtin_amdgcn_global_load_lds(
            (const __attribute__((address_space(1))) void*)src,
            (__attribute__((address_space(3))) void*)dst, 16, 0, 0);
      }
    }
  }

  // Weights (L1-broadcast) with w-edge validity folded; bias.
  const int c4i = tid & 7;
  const int wi1 = tid >> 3;           // 0..15
  const int cofs = cbase + c4i * 4;
  const int wg1 = w0 + wi1;
  const float cs0 = (wg1 >= 1) ? 1.f : 0.f;
  const float cs2 = (wg1 <= Wn - 2) ? 1.f : 0.f;
  floatx4 wv[3][3];
#pragma unroll
  for (int kh = 0; kh < 3; ++kh) {
#pragma unroll
    for (int kw = 0; kw < 3; ++kw)
      wv[kh][kw] = *(const floatx4*)(wgt + (kh * 3 + kw) * Cn + cofs);
    wv[kh][0] *= cs0;
    wv[kh][2] *= cs2;
  }
  const floatx4 bv = *(const floatx4*)(bias + cofs);
  const float sTop = (hg == 0) ? 0.f : 1.f;       // staged row 0 validity
  const float sBot = (hg == HG - 1) ? 0.f : 1.f;  // staged row 57 validity

  const int ostr = Wn * C4;  // 5376 f4 per output row
  floatx4* outp = (floatx4*)out +
      ((long)b * Hn + hbase) * ostr + (long)wg1 * C4 + c4t * CT + c4i;
  // Consume address: f4 offset within region-row = wi1*CT + c4i = tid.

#pragma unroll
  for (int t = 0; t < NSTEP; ++t) {
    // Issue region t+3 (depth-2 prefetch) into slot (t+3)&3 — that slot
    // held region t-1, fully read before last tile's end barrier.
    if (t + 3 <= NSTEP) {
      const int k = t + 3;
      char* rbase = (char*)lds + (k & 3) * REGB;
#pragma unroll
      for (int j = 0; j < 5; ++j) {
        if (j < ccount) {
          int h = hbase + 4 * k + rr[j] - 1;  // >= 11: bottom clamp only
          int hc = min(h, Hn - 1);
          const float* src = xb + (long)hc * rstr + colOff[j];
          __builtin_amdgcn_global_load_lds(
              (const __attribute__((address_space(1))) void*)src,
              (__attribute__((address_space(3))) void*)(rbase + (cstart + j) * 1024),
              16, 0, 0);
        }
      }
    }
    // Counted waits: drain exactly through region t+1 (needed this tile);
    // keep later regions + recent stores in flight. Derived per schedule:
    //   t=0:  keep {R2,R3}            -> 10 / 8
    //   t=1:  keep {R3,st0,R4}        -> 14 / 12
    //   2..11: keep {st,R+2,st,R+3}   -> 18 / 16
    //   t=12: keep {st10,R14,st11}    -> 13 / 12
    //   t=13: keep {st11,st12}        -> 8
    if (t == 0)       { if (wave == 0) VMWAIT(10); else VMWAIT(8); }
    else if (t == 1)  { if (wave == 0) VMWAIT(14); else VMWAIT(12); }
    else if (t <= 11) { if (wave == 0) VMWAIT(18); else VMWAIT(16); }
    else if (t == 12) { if (wave == 0) VMWAIT(13); else VMWAIT(12); }
    else              { VMWAIT(8); }
    __builtin_amdgcn_s_barrier();

    floatx4 acc[4];
#pragma unroll
    for (int o = 0; o < 4; ++o) acc[o] = bv;

    // Staged rows 4t..4t+5: r<4 -> region t rowoff r; r>=4 -> region t+1
    // rowoff r-4. All slot/row offsets compile-time after unroll.
#pragma unroll
    for (int r = 0; r < 6; ++r) {
      const int reg = (r < 4) ? t : t + 1;
      const int rowoff = (r < 4) ? r : r - 4;
      const floatx4* base = lds + (reg & 3) * REGF4 + rowoff * ROWF4 + tid;
      floatx4 xv0 = base[0];
      floatx4 xv1 = base[CT];
      floatx4 xv2 = base[2 * CT];
      if (t == 0 && r == 0) { xv0 *= sTop; xv1 *= sTop; xv2 *= sTop; }
      if (t == NSTEP - 1 && r == 5) { xv0 *= sBot; xv1 *= sBot; xv2 *= sBot; }
#pragma unroll
      for (int kh = 0; kh < 3; ++kh) {
        int o = r - kh;
        if (o >= 0 && o < 4) {
          acc[o] = fma4(xv0, wv[kh][0], acc[o]);
          acc[o] = fma4(xv1, wv[kh][1], acc[o]);
          acc[o] = fma4(xv2, wv[kh][2], acc[o]);
        }
      }
    }

#pragma unroll
    for (int o = 0; o < 4; ++o)
      __builtin_nontemporal_store(acc[o], outp + (long)(4 * t + o) * ostr);

    // End-of-tile barrier: all waves done reading before the slot recycled
    // by the NEXT tile's issue (placed after this barrier) is overwritten.
    __builtin_amdgcn_s_barrier();
  }
}

extern "C" void kernel_launch(void* const* d_in, const int* in_sizes, int n_in,
                              void* d_out, int out_size, void* d_ws, size_t ws_size,
                              hipStream_t stream) {
  const float* x = (const float*)d_in[0];
  const float* w = (const float*)d_in[1];
  const float* b = (const float*)d_in[2];
  float* out = (float*)d_out;

  const int grid = Bn * HG * WTiles * CTiles;  // 2688, divisible by 8
  dwconv3x3_deep<<<grid, 128, 0, stream>>>(x, w, b, out);
}

// Round 9
// 109.786 us; speedup vs baseline: 1.0683x; 1.0683x over previous
//
#include <hip/hip_runtime.h>

// Depthwise 3x3 conv, NHWC, stride 1, SAME, fp32.
// x: (32,112,112,192), w: (3,3,1,192), b: (192), out: (32,112,112,192)
//
// R9: max waves/CU. HT=2 rows/tile, ring = 8 rows x 18 cols x 16 c4
//     (36,864 B) -> 4 blocks/CU = 16 waves/CU (R6: 12 -> 107us; R7/R8: 8 ->
//     115/117us). One barrier per tile: order [wait, barrier, stage(2t+6,7),
//     consume, store] makes slot recycling race-free (stage(t) targets slots
//     last read at consume(t-1), complete before barrier(t)). Depth-2 slack:
//     rows consumed at t were issued at t-2. Counted vmcnt never 0.

constexpr int Bn = 32, Hn = 112, Wn = 112, Cn = 192, C4 = 48;
constexpr int WT = 16, CT = 16;
constexpr int WTiles = 7, CTiles = 3;
constexpr int NSTEP = 14, HG = 4;     // 28 output rows per block
constexpr int LWC = 18;               // staged halo cols
constexpr int ROWF4 = LWC * CT;       // 288 f4 per staged row
constexpr int ROWB = ROWF4 * 16;      // 4608 B
constexpr int NSLOT = 8;              // ring rows; 36,864 B LDS

typedef float floatx4 __attribute__((ext_vector_type(4)));

#define VMWAIT(n) asm volatile("s_waitcnt vmcnt(" #n ")" ::: "memory")

__device__ __forceinline__ floatx4 fma4(floatx4 a, floatx4 b, floatx4 c) {
  c.x = fmaf(a.x, b.x, c.x);
  c.y = fmaf(a.y, b.y, c.y);
  c.z = fmaf(a.z, b.z, c.z);
  c.w = fmaf(a.w, b.w, c.w);
  return c;
}

__global__ __launch_bounds__(256, 4) void dwconv3x3_ring8(
    const float* __restrict__ x,
    const float* __restrict__ wgt,   // (3,3,1,192)
    const float* __restrict__ bias,  // (192)
    float* __restrict__ out) {
  __shared__ floatx4 lds[NSLOT * ROWF4];  // 36,864 B
  const int tid = (int)threadIdx.x;
  const int lane = tid & 63;
  const int wave = tid >> 6;

  // Chunked XCD swizzle (2688 % 8 == 0).
  int bid = blockIdx.x;
  int chk = gridDim.x >> 3;  // 336
  int sbid = (bid & 7) * chk + (bid >> 3);
  int c4t = sbid % CTiles; int tt = sbid / CTiles;
  int wt = tt % WTiles;    tt /= WTiles;
  int hg = tt % HG;        int b = tt / HG;

  const int hbase = hg * (2 * NSTEP);
  const int w0 = wt * WT;
  const int cbase = c4t * (CT * 4);
  const float* xb = x + (long)b * Hn * Wn * Cn;
  const int rstr = Wn * Cn;

  // 2-row stage group = 576 f4 = 9 chunks, waves own {3,2,2,2}:
  const int cstart2 = wave ? (1 + 2 * wave) : 0;   // 0,3,5,7
  const int bcnt = wave ? 2 : 3;
  int rr2[3], colOff2[3];
#pragma unroll
  for (int j = 0; j < 3; ++j) {
    int l = (cstart2 + j) * 64 + lane;   // f4 linear in 2-row group
    int r2 = (l >= ROWF4) ? 1 : 0;
    int rem = l - r2 * ROWF4;
    int wi = rem >> 4, c4l = rem & 15;
    int wg = w0 + wi - 1;
    int wc = min(max(wg, 0), Wn - 1);    // clamp; w-validity in weights
    rr2[j] = r2;
    colOff2[j] = wc * Cn + cbase + c4l * 4;
  }

  // Staged row s (0..29) = input h = hbase + s - 1. Tile t consumes rows
  // 2t..2t+3 (outputs 2t,2t+1); stage(t) lands rows 2t+6,2t+7 (t<=11).
  // Prologue: rows 0..3 (18 chunks {5,5,4,4}) then rows 4,5 (pair group).
  {
    const int cstart4 = (wave < 2) ? wave * 5 : 10 + (wave - 2) * 4;
    const int acnt = (wave < 2) ? 5 : 4;
#pragma unroll
    for (int j = 0; j < 5; ++j) {
      if (j < acnt) {
        int chunk = cstart4 + j;
        int l = chunk * 64 + lane;       // 0..1151 over 4 rows
        int r4 = l / ROWF4;
        int rem = l - r4 * ROWF4;
        int wi = rem >> 4, c4l = rem & 15;
        int h = hbase + r4 - 1;
        int hc = min(max(h, 0), Hn - 1);
        int wg = w0 + wi - 1;
        int wc = min(max(wg, 0), Wn - 1);
        const float* src = xb + (long)hc * rstr + wc * Cn + cbase + c4l * 4;
        char* dst = (char*)lds + chunk * 1024;   // slots 0..3 contiguous
        __builtin_amdgcn_global_load_lds(
            (const __attribute__((address_space(1))) void*)src,
            (__attribute__((address_space(3))) void*)dst, 16, 0, 0);
      }
    }
    // rows 4,5 -> slots 4,5
#pragma unroll
    for (int j = 0; j < 3; ++j) {
      if (j < bcnt) {
        int h = hbase + 4 + rr2[j] - 1;  // >= 3, no top clamp needed
        const float* src = xb + (long)h * rstr + colOff2[j];
        char* dst = (char*)lds + 4 * ROWB + (cstart2 + j) * 1024;
        __builtin_amdgcn_global_load_lds(
            (const __attribute__((address_space(1))) void*)src,
            (__attribute__((address_space(3))) void*)dst, 16, 0, 0);
      }
    }
  }

  // Weights (L1-broadcast) with w-edge validity folded; bias.
  const int c4i = tid & 15;
  const int wi1 = tid >> 4;
  const int cofs = cbase + c4i * 4;
  const int wg1 = w0 + wi1;
  const float cs0 = (wg1 >= 1) ? 1.f : 0.f;
  const float cs2 = (wg1 <= Wn - 2) ? 1.f : 0.f;
  floatx4 wv[3][3];
#pragma unroll
  for (int kh = 0; kh < 3; ++kh) {
#pragma unroll
    for (int kw = 0; kw < 3; ++kw)
      wv[kh][kw] = *(const floatx4*)(wgt + (kh * 3 + kw) * Cn + cofs);
    wv[kh][0] *= cs0;
    wv[kh][2] *= cs2;
  }
  const floatx4 bv = *(const floatx4*)(bias + cofs);
  const float sTop = (hg == 0) ? 0.f : 1.f;       // staged row 0
  const float sBot = (hg == HG - 1) ? 0.f : 1.f;  // staged row 29

  const int ostr = Wn * C4;  // 5376 f4 per output row
  floatx4* outp = (floatx4*)out +
      ((long)b * Hn + hbase) * ostr + (long)wg1 * C4 + c4t * CT + c4i;

#pragma unroll
  for (int t = 0; t < NSTEP; ++t) {
    // Counted wait: drain exactly the rows tile t consumes (issued 2 tiles
    // ago); keep later loads + stores in flight. Never 0 mid-kernel.
    if (t == 0)       { if (wave == 0) VMWAIT(3); else VMWAIT(2); }
    else if (t == 1)  { if (wave == 0) VMWAIT(5); else VMWAIT(4); }
    else if (t < 13)  { if (wave == 0) VMWAIT(7); else VMWAIT(6); }
    else              { VMWAIT(4); }
    __builtin_amdgcn_s_barrier();

    // Stage rows 2t+6, 2t+7 into slots (2t+6)%8, +1. Safe post-barrier:
    // those slots were last read at consume(t-1), complete before barrier.
    if (t <= 11) {
      const int s0 = 2 * t + 6;
      char* rbase = (char*)lds + (s0 & 7) * ROWB;
#pragma unroll
      for (int j = 0; j < 3; ++j) {
        if (j < bcnt) {
          int h = hbase + s0 + rr2[j] - 1;   // >= 5; bottom clamp only
          int hc = min(h, Hn - 1);
          const float* src = xb + (long)hc * rstr + colOff2[j];
          __builtin_amdgcn_global_load_lds(
              (const __attribute__((address_space(1))) void*)src,
              (__attribute__((address_space(3))) void*)(rbase + (cstart2 + j) * 1024),
              16, 0, 0);
        }
      }
    }

    floatx4 acc[2] = {bv, bv};
    // Staged rows 2t+r, r=0..3; output o uses kh = r - o in [0,2].
#pragma unroll
    for (int r = 0; r < 4; ++r) {
      const int slot = (2 * t + r) & 7;     // compile-time after unroll
      const floatx4* base = lds + slot * ROWF4 + tid;
      floatx4 xv0 = base[0];
      floatx4 xv1 = base[CT];
      floatx4 xv2 = base[2 * CT];
      if (t == 0 && r == 0) { xv0 *= sTop; xv1 *= sTop; xv2 *= sTop; }
      if (t == NSTEP - 1 && r == 3) { xv0 *= sBot; xv1 *= sBot; xv2 *= sBot; }
#pragma unroll
      for (int o = 0; o < 2; ++o) {
        int kh = r - o;
        if (kh >= 0 && kh < 3) {
          acc[o] = fma4(xv0, wv[kh][0], acc[o]);
          acc[o] = fma4(xv1, wv[kh][1], acc[o]);
          acc[o] = fma4(xv2, wv[kh][2], acc[o]);
        }
      }
    }

#pragma unroll
    for (int o = 0; o < 2; ++o)
      __builtin_nontemporal_store(acc[o], outp + (long)(2 * t + o) * ostr);
  }
}

extern "C" void kernel_launch(void* const* d_in, const int* in_sizes, int n_in,
                              void* d_out, int out_size, void* d_ws, size_t ws_size,
                              hipStream_t stream) {
  const float* x = (const float*)d_in[0];
  const float* w = (const float*)d_in[1];
  const float* b = (const float*)d_in[2];
  float* out = (float*)d_out;

  const int grid = Bn * HG * WTiles * CTiles;  // 2688, divisible by 8
  dwconv3x3_ring8<<<grid, 256, 0, stream>>>(x, w, b, out);
}